// Round 5
// baseline (271.837 us; speedup 1.0000x reference)
//
#include <hip/hip_runtime.h>

// ConnectivityLoss R5: wave-slab register skeletonize, latency-optimized.
// - 4 blocks/CU (launch_bounds(256,4)), LDS 39.7KB.
// - Lane layout s=lane>>3 (col strip), gq=lane&7 (row group): vertical
//   neighbor exchange = DPP row_shr/shl:1 (VALU pipe, free of LDS);
//   horizontal le/ri = ds_bpermute lane+-8 (10 LDS ops/pass, down from 26).
// - Rolling-column epilogue: 8 LDS reads/px instead of 18.

#define IMG 512
#define TW  32            // output tile width  (16 x-tiles)
#define TH  128           // output tile height (4 y-tiles)
#define SKW 34            // skeleton stash cols [11,44]
#define SKH 130           // skeleton stash rows [11,140]
#define XROW 68           // exchange row stride (floats)
#define XBUF (8*XROW)     // 4 waves x {top,bot}
#define NT  256

struct alignas(16) R8 { float v[8]; };

__device__ __forceinline__ float f3min(float a, float b, float c) {
    return fminf(fminf(a, b), c);
}
__device__ __forceinline__ float f3max(float a, float b, float c) {
    return fmaxf(fmaxf(a, b), c);
}
__device__ __forceinline__ float dpp_up1(float x) {   // lane i <- i-1
    int r = __builtin_amdgcn_update_dpp(
        0, __builtin_bit_cast(int, x), 0x111, 0xF, 0xF, true); // row_shr:1
    return __builtin_bit_cast(float, r);
}
__device__ __forceinline__ float dpp_dn1(float x) {   // lane i <- i+1
    int r = __builtin_amdgcn_update_dpp(
        0, __builtin_bit_cast(int, x), 0x101, 0xF, 0xF, true); // row_shl:1
    return __builtin_bit_cast(float, r);
}
__device__ __forceinline__ float bpermf(int addr, float x) {
    return __builtin_bit_cast(float,
        __builtin_amdgcn_ds_bpermute(addr, __builtin_bit_cast(int, x)));
}

// horizontal 3-tap; le/ri from strip s-1/s+1 (lane -8/+8, precomputed addrs).
// fixL/fixR: clamped-window at image cols 0/511.
template<bool MN>
__device__ __forceinline__ void hrow(const R8& r, R8& h, bool fixL, bool fixR,
                                     int aL, int aR) {
    float le = bpermf(aL, r.v[7]);
    float ri = bpermf(aR, r.v[0]);
    if (MN) {
        h.v[0] = f3min(le,     r.v[0], r.v[1]);
        h.v[1] = f3min(r.v[0], r.v[1], r.v[2]);
        h.v[2] = f3min(r.v[1], r.v[2], r.v[3]);
        h.v[3] = f3min(r.v[2], r.v[3], r.v[4]);
        h.v[4] = f3min(r.v[3], r.v[4], r.v[5]);
        h.v[5] = f3min(r.v[4], r.v[5], r.v[6]);
        h.v[6] = f3min(r.v[5], r.v[6], r.v[7]);
        h.v[7] = f3min(r.v[6], r.v[7], ri);
        if (fixL) h.v[4] = fminf(r.v[4], r.v[5]);   // gx==0
        if (fixR) h.v[3] = fminf(r.v[2], r.v[3]);   // gx==511
    } else {
        h.v[0] = f3max(le,     r.v[0], r.v[1]);
        h.v[1] = f3max(r.v[0], r.v[1], r.v[2]);
        h.v[2] = f3max(r.v[1], r.v[2], r.v[3]);
        h.v[3] = f3max(r.v[2], r.v[3], r.v[4]);
        h.v[4] = f3max(r.v[3], r.v[4], r.v[5]);
        h.v[5] = f3max(r.v[4], r.v[5], r.v[6]);
        h.v[6] = f3max(r.v[5], r.v[6], r.v[7]);
        h.v[7] = f3max(r.v[6], r.v[7], ri);
        if (fixL) h.v[4] = fmaxf(r.v[4], r.v[5]);
        if (fixR) h.v[3] = fmaxf(r.v[2], r.v[3]);
    }
}

__global__ __launch_bounds__(NT, 4)
void skel_conn_loss(const float* __restrict__ pred,
                    const float* __restrict__ target,
                    float* __restrict__ out)
{
    __shared__ float X[2*XBUF];          // boundary-row exchange dbuf (4.35KB)
    __shared__ float SKP[SKH*SKW];       // pred skeleton
    __shared__ float SKT[SKH*SKW];       // target skeleton
    __shared__ float red[4];

    const int tid  = threadIdx.x;
    const int wv   = tid >> 6;           // wave 0..3 owns rows 40w..40w+39
    const int lane = tid & 63;
    const int s    = lane >> 3;          // 8-col strip
    const int gq   = lane & 7;           // row group (5 rows); +-1 == lane+-1
    const int img  = blockIdx.x >> 6;
    const int rem  = blockIdx.x & 63;
    const int ty0  = (rem >> 4) * TH;
    const int tx0  = (rem & 15) * TW;

    const int c0  = 8*s;
    const int r0  = 40*wv + 5*gq;
    const int gx0 = tx0 - 12 + c0;
    const bool xin = (tx0 > 0) && (tx0 + TW < IMG);

    const bool lB = (tx0 == 0), rB = (tx0 + TW == IMG);
    const bool tB = (ty0 == 0), bB = (ty0 + TH == IMG);
    const bool fixL = lB && (s == 1);                // col 12 == gx 0
    const bool fixR = rB && (s == 5);                // col 43 == gx 511
    const bool vfT  = tB && (wv == 0) && (gq == 2);  // row 12 == gy 0 (i==2)
    const bool vfB  = bB && (wv == 3) && (gq == 3);  // row 139 == gy 511 (i==4)
    const int  sw   = 8*s + 4*(s >> 2);              // bank-swizzled exch col
    const int  aL   = ((lane - 8) & 63) * 4;         // bpermute addrs
    const int  aR   = ((lane + 8) & 63) * 4;

    R8 A[5], Bv[5];
    int xb = 0;

    #pragma unroll 1
    for (int t = 0; t < 2; ++t) {
        const float* __restrict__ src =
            (t ? target : pred) + (size_t)img * (IMG * IMG);

        // ---- load strip (addresses clamped; OOB values never consumed) ----
        #pragma unroll
        for (int i = 0; i < 5; ++i) {
            int gy = min(max(ty0 - 12 + r0 + i, 0), IMG - 1);
            const float* rp = src + gy * IMG;
            if (xin) {
                *(float4*)&A[i].v[0] = *(const float4*)(rp + gx0);
                *(float4*)&A[i].v[4] = *(const float4*)(rp + gx0 + 4);
            } else {
                #pragma unroll
                for (int j = 0; j < 8; ++j)
                    A[i].v[j] = rp[min(max(gx0 + j, 0), IMG - 1)];
            }
        }

        #pragma unroll 1
        for (int it = 0; it < 5; ++it) {
            // ================= pass 1: Bv = minpool3(A) =================
            {
                R8 w[5], abh, beh;
                #pragma unroll
                for (int i = 0; i < 5; ++i)
                    hrow<true>(A[i], w[i], fixL, fixR, aL, aR);
                float* Xb = X + xb * XBUF;
                if (gq == 0) {
                    float* p = Xb + (2*wv) * XROW + sw;
                    *(float4*)p       = *(const float4*)&w[0].v[0];
                    *(float4*)(p + 4) = *(const float4*)&w[0].v[4];
                }
                if (gq == 7) {
                    float* p = Xb + (2*wv + 1) * XROW + sw;
                    *(float4*)p       = *(const float4*)&w[4].v[0];
                    *(float4*)(p + 4) = *(const float4*)&w[4].v[4];
                }
                __syncthreads();
                #pragma unroll
                for (int j = 0; j < 8; ++j) {
                    abh.v[j] = dpp_up1(w[4].v[j]);   // group above's bottom
                    beh.v[j] = dpp_dn1(w[0].v[j]);   // group below's top
                }
                if (gq == 0) {
                    if (wv) {
                        const float* p = Xb + (2*wv - 1) * XROW + sw;
                        *(float4*)&abh.v[0] = *(const float4*)p;
                        *(float4*)&abh.v[4] = *(const float4*)(p + 4);
                    } else abh = w[0];               // tile-edge garbage margin
                }
                if (gq == 7) {
                    if (wv < 3) {
                        const float* p = Xb + (2*wv + 2) * XROW + sw;
                        *(float4*)&beh.v[0] = *(const float4*)p;
                        *(float4*)&beh.v[4] = *(const float4*)(p + 4);
                    } else beh = w[4];
                }
                #pragma unroll
                for (int j = 0; j < 8; ++j) {
                    Bv[0].v[j] = f3min(abh.v[j], w[0].v[j], w[1].v[j]);
                    Bv[1].v[j] = f3min(w[0].v[j], w[1].v[j], w[2].v[j]);
                    Bv[2].v[j] = vfT ? fminf(w[2].v[j], w[3].v[j])
                                     : f3min(w[1].v[j], w[2].v[j], w[3].v[j]);
                    Bv[3].v[j] = f3min(w[2].v[j], w[3].v[j], w[4].v[j]);
                    Bv[4].v[j] = vfB ? fminf(w[3].v[j], w[4].v[j])
                                     : f3min(w[3].v[j], w[4].v[j], beh.v[j]);
                }
                xb ^= 1;
            }
            // ====== pass 2: A = relu(A - relu(maxpool3(Bv) - Bv)) ======
            {
                R8 u[5], abh, beh;
                #pragma unroll
                for (int i = 0; i < 5; ++i)
                    hrow<false>(Bv[i], u[i], fixL, fixR, aL, aR);
                float* Xb = X + xb * XBUF;
                if (gq == 0) {
                    float* p = Xb + (2*wv) * XROW + sw;
                    *(float4*)p       = *(const float4*)&u[0].v[0];
                    *(float4*)(p + 4) = *(const float4*)&u[0].v[4];
                }
                if (gq == 7) {
                    float* p = Xb + (2*wv + 1) * XROW + sw;
                    *(float4*)p       = *(const float4*)&u[4].v[0];
                    *(float4*)(p + 4) = *(const float4*)&u[4].v[4];
                }
                __syncthreads();
                #pragma unroll
                for (int j = 0; j < 8; ++j) {
                    abh.v[j] = dpp_up1(u[4].v[j]);
                    beh.v[j] = dpp_dn1(u[0].v[j]);
                }
                if (gq == 0) {
                    if (wv) {
                        const float* p = Xb + (2*wv - 1) * XROW + sw;
                        *(float4*)&abh.v[0] = *(const float4*)p;
                        *(float4*)&abh.v[4] = *(const float4*)(p + 4);
                    } else abh = u[0];
                }
                if (gq == 7) {
                    if (wv < 3) {
                        const float* p = Xb + (2*wv + 2) * XROW + sw;
                        *(float4*)&beh.v[0] = *(const float4*)p;
                        *(float4*)&beh.v[4] = *(const float4*)(p + 4);
                    } else beh = u[4];
                }
                #define UPD(i, MXE)                                            \
                    _Pragma("unroll")                                          \
                    for (int j = 0; j < 8; ++j) {                              \
                        float mx = (MXE);                                      \
                        float ct = fmaxf(mx - Bv[i].v[j], 0.0f);               \
                        A[i].v[j] = fmaxf(A[i].v[j] - ct, 0.0f);               \
                    }
                UPD(0, f3max(abh.v[j], u[0].v[j], u[1].v[j]))
                UPD(1, f3max(u[0].v[j], u[1].v[j], u[2].v[j]))
                UPD(2, vfT ? fmaxf(u[2].v[j], u[3].v[j])
                           : f3max(u[1].v[j], u[2].v[j], u[3].v[j]))
                UPD(3, f3max(u[2].v[j], u[3].v[j], u[4].v[j]))
                UPD(4, vfB ? fmaxf(u[3].v[j], u[4].v[j])
                           : f3max(u[3].v[j], u[4].v[j], beh.v[j]))
                #undef UPD
                xb ^= 1;
            }
        }

        // ---- stash skeleton region [11,140]x[11,44] to LDS ----
        {
            float* SK = t ? SKT : SKP;
            #pragma unroll
            for (int i = 0; i < 5; ++i) {
                int pr = r0 + i;
                if (pr >= 11 && pr <= 140) {
                    #pragma unroll
                    for (int j = 0; j < 8; ++j) {
                        int pc = c0 + j;
                        if (pc >= 11 && pc <= 44)
                            SK[(pr - 11) * SKW + (pc - 11)] = A[i].v[j];
                    }
                }
            }
        }
    }
    __syncthreads();

    // ---- epilogue: rolling-column sumpool3 + indicators + loss ----
    // thread = column cx, 16 rows. SK row k holds global row ty0 + k - 1.
    const int cx  = tid & 31;
    const int ry0 = (tid >> 5) * 16;
    const int gx  = tx0 + cx;
    const float xl = (gx >= 1)      ? 1.0f : 0.0f;
    const float xr = (gx + 1 < IMG) ? 1.0f : 0.0f;

    auto hs = [&](const float* __restrict__ SK, int k) -> float {
        const float* p = SK + k * SKW + cx;   // p[0]=dx-1, p[1]=dx0, p[2]=dx+1
        return p[1] + xl * p[0] + xr * p[2];  // garbage finite, masked by 0
    };

    float acc = 0.0f;
    float hp0, hp1, ht0, ht1;
    {
        float vT = ((unsigned)(ty0 + ry0 - 1) < IMG) ? 1.0f : 0.0f;
        hp0 = vT * hs(SKP, ry0);
        ht0 = vT * hs(SKT, ry0);
        hp1 = hs(SKP, ry0 + 1);               // always in-image
        ht1 = hs(SKT, ry0 + 1);
    }
    #pragma unroll
    for (int r = 0; r < 16; ++r) {
        int k2 = ry0 + r + 2;
        float vB = ((unsigned)(ty0 + k2 - 1) < IMG) ? 1.0f : 0.0f;
        float hp2 = vB * hs(SKP, k2);
        float ht2 = vB * hs(SKT, k2);
        float pn = hp0 + hp1 + hp2;
        float tn = ht0 + ht1 + ht2;
        float ps = SKP[(ry0 + r + 1) * SKW + cx + 1];
        float ts = SKT[(ry0 + r + 1) * SKW + cx + 1];
        float pon = (ps > 0.5f) ? 1.0f : 0.0f;
        float ton = (ts > 0.5f) ? 1.0f : 0.0f;
        float pe = (pn == 2.0f) ? pon : 0.0f;
        float te = (tn == 2.0f) ? ton : 0.0f;
        float pc = (pn >= 4.0f) ? pon : 0.0f;
        float tc = (tn >= 4.0f) ? ton : 0.0f;
        float ds = ps - ts, de = pe - te, dc = pc - tc;
        acc += 0.6f * ds * ds + 0.2f * (de * de + dc * dc);
        hp0 = hp1; hp1 = hp2;
        ht0 = ht1; ht1 = ht2;
    }

    #pragma unroll
    for (int off = 32; off >= 1; off >>= 1)
        acc += __shfl_down(acc, off, 64);
    if ((tid & 63) == 0) red[tid >> 6] = acc;
    __syncthreads();
    if (tid == 0) {
        float sum = red[0] + red[1] + red[2] + red[3];
        atomicAdd(out, sum * (1.0f / 8388608.0f));  // N = 32*512*512 = 2^23
    }
}

extern "C" void kernel_launch(void* const* d_in, const int* in_sizes, int n_in,
                              void* d_out, int out_size, void* d_ws, size_t ws_size,
                              hipStream_t stream) {
    const float* pred   = (const float*)d_in[0];
    const float* target = (const float*)d_in[1];
    float* out = (float*)d_out;
    hipMemsetAsync(d_out, 0, sizeof(float) * (out_size > 0 ? out_size : 1), stream);
    const int nblocks = 32 * 64;   // 32 images x (4x16) tiles
    skel_conn_loss<<<nblocks, NT, 0, stream>>>(pred, target, out);
}

// Round 6
// 193.376 us; speedup vs baseline: 1.4057x; 1.4057x over previous
//
#include <hip/hip_runtime.h>

// ConnectivityLoss R6: R5 structure with spill-free register economics.
// - launch_bounds(256,3): 168-VGPR cap (R5's (256,4) caused a spill cascade:
//   VGPR 64 + 415 MB scratch traffic = the whole runtime).
// - Rolling-window passes: w4/w0 computed first (feed exchange+DPP), barrier
//   early, w1..w3 interleaved with vertical combines. Peak live ~115 floats.
// - Vertical +-1-group exchange via DPP row_shr/shl (VALU pipe); horizontal
//   via ds_bpermute lane+-8; wave-boundary rows via tiny swizzled LDS dbuf.
// - Image borders exact via clamped-window tap-dropping.

#define IMG 512
#define TW  32            // output tile width  (16 x-tiles)
#define TH  128           // output tile height (4 y-tiles)
#define SKW 34            // skeleton stash cols [11,44]
#define SKH 130           // skeleton stash rows [11,140]
#define XROW 68           // exchange row stride (floats)
#define XBUF (8*XROW)     // 4 waves x {top,bot}
#define NT  256

struct alignas(16) R8 { float v[8]; };

__device__ __forceinline__ float f3min(float a, float b, float c) {
    return fminf(fminf(a, b), c);
}
__device__ __forceinline__ float f3max(float a, float b, float c) {
    return fmaxf(fmaxf(a, b), c);
}
__device__ __forceinline__ float dpp_up1(float x) {   // lane i <- i-1
    int r = __builtin_amdgcn_update_dpp(
        0, __builtin_bit_cast(int, x), 0x111, 0xF, 0xF, true); // row_shr:1
    return __builtin_bit_cast(float, r);
}
__device__ __forceinline__ float dpp_dn1(float x) {   // lane i <- i+1
    int r = __builtin_amdgcn_update_dpp(
        0, __builtin_bit_cast(int, x), 0x101, 0xF, 0xF, true); // row_shl:1
    return __builtin_bit_cast(float, r);
}
__device__ __forceinline__ float bpermf(int addr, float x) {
    return __builtin_bit_cast(float,
        __builtin_amdgcn_ds_bpermute(addr, __builtin_bit_cast(int, x)));
}

// horizontal 3-tap; le/ri from strip s-1/s+1 (lane -8/+8, precomputed addrs).
// fixL/fixR: clamped-window at image cols 0/511 (drop out-of-image tap).
template<bool MN>
__device__ __forceinline__ void hrow(const R8& r, R8& h, bool fixL, bool fixR,
                                     int aL, int aR) {
    float le = bpermf(aL, r.v[7]);
    float ri = bpermf(aR, r.v[0]);
    if (MN) {
        h.v[0] = f3min(le,     r.v[0], r.v[1]);
        h.v[1] = f3min(r.v[0], r.v[1], r.v[2]);
        h.v[2] = f3min(r.v[1], r.v[2], r.v[3]);
        h.v[3] = f3min(r.v[2], r.v[3], r.v[4]);
        h.v[4] = f3min(r.v[3], r.v[4], r.v[5]);
        h.v[5] = f3min(r.v[4], r.v[5], r.v[6]);
        h.v[6] = f3min(r.v[5], r.v[6], r.v[7]);
        h.v[7] = f3min(r.v[6], r.v[7], ri);
        if (fixL) h.v[4] = fminf(r.v[4], r.v[5]);   // gx==0
        if (fixR) h.v[3] = fminf(r.v[2], r.v[3]);   // gx==511
    } else {
        h.v[0] = f3max(le,     r.v[0], r.v[1]);
        h.v[1] = f3max(r.v[0], r.v[1], r.v[2]);
        h.v[2] = f3max(r.v[1], r.v[2], r.v[3]);
        h.v[3] = f3max(r.v[2], r.v[3], r.v[4]);
        h.v[4] = f3max(r.v[3], r.v[4], r.v[5]);
        h.v[5] = f3max(r.v[4], r.v[5], r.v[6]);
        h.v[6] = f3max(r.v[5], r.v[6], r.v[7]);
        h.v[7] = f3max(r.v[6], r.v[7], ri);
        if (fixL) h.v[4] = fmaxf(r.v[4], r.v[5]);
        if (fixR) h.v[3] = fmaxf(r.v[2], r.v[3]);
    }
}

__global__ __launch_bounds__(NT, 3)
void skel_conn_loss(const float* __restrict__ pred,
                    const float* __restrict__ target,
                    float* __restrict__ out)
{
    __shared__ float X[2*XBUF];          // boundary-row exchange dbuf (4.35KB)
    __shared__ float SKP[SKH*SKW];       // pred skeleton
    __shared__ float SKT[SKH*SKW];       // target skeleton
    __shared__ float red[4];

    const int tid  = threadIdx.x;
    const int wv   = tid >> 6;           // wave 0..3 owns rows 40w..40w+39
    const int lane = tid & 63;
    const int s    = lane >> 3;          // 8-col strip
    const int gq   = lane & 7;           // row group (5 rows); +-1 == lane+-1
    const int img  = blockIdx.x >> 6;
    const int rem  = blockIdx.x & 63;
    const int ty0  = (rem >> 4) * TH;
    const int tx0  = (rem & 15) * TW;

    const int c0  = 8*s;
    const int r0  = 40*wv + 5*gq;
    const int gx0 = tx0 - 12 + c0;
    const bool xin = (tx0 > 0) && (tx0 + TW < IMG);

    const bool lB = (tx0 == 0), rB = (tx0 + TW == IMG);
    const bool tB = (ty0 == 0), bB = (ty0 + TH == IMG);
    const bool fixL = lB && (s == 1);                // col 12 == gx 0
    const bool fixR = rB && (s == 5);                // col 43 == gx 511
    const bool vfT  = tB && (wv == 0) && (gq == 2);  // row 12 == gy 0 (i==2)
    const bool vfB  = bB && (wv == 3) && (gq == 3);  // row 139 == gy 511 (i==4)
    const int  sw   = 8*s + 4*(s >> 2);              // bank-swizzled exch col
    const int  aL   = ((lane - 8) & 63) * 4;         // bpermute addrs
    const int  aR   = ((lane + 8) & 63) * 4;

    R8 A[5], Bv[5];
    int xb = 0;

    #pragma unroll 1
    for (int t = 0; t < 2; ++t) {
        const float* __restrict__ src =
            (t ? target : pred) + (size_t)img * (IMG * IMG);

        // ---- load strip (addresses clamped; OOB values never consumed) ----
        #pragma unroll
        for (int i = 0; i < 5; ++i) {
            int gy = min(max(ty0 - 12 + r0 + i, 0), IMG - 1);
            const float* rp = src + gy * IMG;
            if (xin) {
                *(float4*)&A[i].v[0] = *(const float4*)(rp + gx0);
                *(float4*)&A[i].v[4] = *(const float4*)(rp + gx0 + 4);
            } else {
                #pragma unroll
                for (int j = 0; j < 8; ++j)
                    A[i].v[j] = rp[min(max(gx0 + j, 0), IMG - 1)];
            }
        }

        #pragma unroll 1
        for (int it = 0; it < 5; ++it) {
            // ================= pass 1: Bv = minpool3(A) =================
            {
                R8 w0, w1, w2, w3, w4, abh, beh;
                hrow<true>(A[4], w4, fixL, fixR, aL, aR);   // feeds exch+DPP
                hrow<true>(A[0], w0, fixL, fixR, aL, aR);
                float* Xb = X + xb * XBUF;
                if (gq == 0) {
                    float* p = Xb + (2*wv) * XROW + sw;
                    *(float4*)p       = *(const float4*)&w0.v[0];
                    *(float4*)(p + 4) = *(const float4*)&w0.v[4];
                }
                if (gq == 7) {
                    float* p = Xb + (2*wv + 1) * XROW + sw;
                    *(float4*)p       = *(const float4*)&w4.v[0];
                    *(float4*)(p + 4) = *(const float4*)&w4.v[4];
                }
                __syncthreads();
                #pragma unroll
                for (int j = 0; j < 8; ++j) {
                    abh.v[j] = dpp_up1(w4.v[j]);   // group above's bottom
                    beh.v[j] = dpp_dn1(w0.v[j]);   // group below's top
                }
                if (gq == 0) {
                    if (wv) {
                        const float* p = Xb + (2*wv - 1) * XROW + sw;
                        *(float4*)&abh.v[0] = *(const float4*)p;
                        *(float4*)&abh.v[4] = *(const float4*)(p + 4);
                    } else abh = w0;               // tile-edge garbage margin
                }
                if (gq == 7) {
                    if (wv < 3) {
                        const float* p = Xb + (2*wv + 2) * XROW + sw;
                        *(float4*)&beh.v[0] = *(const float4*)p;
                        *(float4*)&beh.v[4] = *(const float4*)(p + 4);
                    } else beh = w4;
                }
                hrow<true>(A[1], w1, fixL, fixR, aL, aR);
                #pragma unroll
                for (int j = 0; j < 8; ++j)
                    Bv[0].v[j] = f3min(abh.v[j], w0.v[j], w1.v[j]);
                hrow<true>(A[2], w2, fixL, fixR, aL, aR);
                #pragma unroll
                for (int j = 0; j < 8; ++j)
                    Bv[1].v[j] = f3min(w0.v[j], w1.v[j], w2.v[j]);
                hrow<true>(A[3], w3, fixL, fixR, aL, aR);
                #pragma unroll
                for (int j = 0; j < 8; ++j) {
                    Bv[2].v[j] = vfT ? fminf(w2.v[j], w3.v[j])
                                     : f3min(w1.v[j], w2.v[j], w3.v[j]);
                    Bv[3].v[j] = f3min(w2.v[j], w3.v[j], w4.v[j]);
                    Bv[4].v[j] = vfB ? fminf(w3.v[j], w4.v[j])
                                     : f3min(w3.v[j], w4.v[j], beh.v[j]);
                }
                xb ^= 1;
            }
            // ====== pass 2: A = relu(A - relu(maxpool3(Bv) - Bv)) ======
            {
                R8 u0, u1, u2, u3, u4, abh, beh;
                hrow<false>(Bv[4], u4, fixL, fixR, aL, aR);
                hrow<false>(Bv[0], u0, fixL, fixR, aL, aR);
                float* Xb = X + xb * XBUF;
                if (gq == 0) {
                    float* p = Xb + (2*wv) * XROW + sw;
                    *(float4*)p       = *(const float4*)&u0.v[0];
                    *(float4*)(p + 4) = *(const float4*)&u0.v[4];
                }
                if (gq == 7) {
                    float* p = Xb + (2*wv + 1) * XROW + sw;
                    *(float4*)p       = *(const float4*)&u4.v[0];
                    *(float4*)(p + 4) = *(const float4*)&u4.v[4];
                }
                __syncthreads();
                #pragma unroll
                for (int j = 0; j < 8; ++j) {
                    abh.v[j] = dpp_up1(u4.v[j]);
                    beh.v[j] = dpp_dn1(u0.v[j]);
                }
                if (gq == 0) {
                    if (wv) {
                        const float* p = Xb + (2*wv - 1) * XROW + sw;
                        *(float4*)&abh.v[0] = *(const float4*)p;
                        *(float4*)&abh.v[4] = *(const float4*)(p + 4);
                    } else abh = u0;
                }
                if (gq == 7) {
                    if (wv < 3) {
                        const float* p = Xb + (2*wv + 2) * XROW + sw;
                        *(float4*)&beh.v[0] = *(const float4*)p;
                        *(float4*)&beh.v[4] = *(const float4*)(p + 4);
                    } else beh = u4;
                }
                #define UPD(i, MXE)                                            \
                    _Pragma("unroll")                                          \
                    for (int j = 0; j < 8; ++j) {                              \
                        float mx = (MXE);                                      \
                        float ct = fmaxf(mx - Bv[i].v[j], 0.0f);               \
                        A[i].v[j] = fmaxf(A[i].v[j] - ct, 0.0f);               \
                    }
                hrow<false>(Bv[1], u1, fixL, fixR, aL, aR);
                UPD(0, f3max(abh.v[j], u0.v[j], u1.v[j]))
                hrow<false>(Bv[2], u2, fixL, fixR, aL, aR);
                UPD(1, f3max(u0.v[j], u1.v[j], u2.v[j]))
                hrow<false>(Bv[3], u3, fixL, fixR, aL, aR);
                UPD(2, vfT ? fmaxf(u2.v[j], u3.v[j])
                           : f3max(u1.v[j], u2.v[j], u3.v[j]))
                UPD(3, f3max(u2.v[j], u3.v[j], u4.v[j]))
                UPD(4, vfB ? fmaxf(u3.v[j], u4.v[j])
                           : f3max(u3.v[j], u4.v[j], beh.v[j]))
                #undef UPD
                xb ^= 1;
            }
        }

        // ---- stash skeleton region [11,140]x[11,44] to LDS ----
        {
            float* SK = t ? SKT : SKP;
            #pragma unroll
            for (int i = 0; i < 5; ++i) {
                int pr = r0 + i;
                if (pr >= 11 && pr <= 140) {
                    #pragma unroll
                    for (int j = 0; j < 8; ++j) {
                        int pc = c0 + j;
                        if (pc >= 11 && pc <= 44)
                            SK[(pr - 11) * SKW + (pc - 11)] = A[i].v[j];
                    }
                }
            }
        }
    }
    __syncthreads();

    // ---- epilogue: rolling-column sumpool3 + indicators + loss ----
    // thread = column cx, 16 rows. SK row k holds global row ty0 + k - 1.
    const int cx  = tid & 31;
    const int ry0 = (tid >> 5) * 16;
    const int gx  = tx0 + cx;
    const float xl = (gx >= 1)      ? 1.0f : 0.0f;
    const float xr = (gx + 1 < IMG) ? 1.0f : 0.0f;

    auto hs = [&](const float* __restrict__ SK, int k) -> float {
        const float* p = SK + k * SKW + cx;   // p[0]=dx-1, p[1]=dx0, p[2]=dx+1
        return p[1] + xl * p[0] + xr * p[2];  // garbage finite, masked by 0
    };

    float acc = 0.0f;
    float hp0, hp1, ht0, ht1;
    {
        float vT = ((unsigned)(ty0 + ry0 - 1) < IMG) ? 1.0f : 0.0f;
        hp0 = vT * hs(SKP, ry0);
        ht0 = vT * hs(SKT, ry0);
        hp1 = hs(SKP, ry0 + 1);               // always in-image
        ht1 = hs(SKT, ry0 + 1);
    }
    #pragma unroll
    for (int r = 0; r < 16; ++r) {
        int k2 = ry0 + r + 2;
        float vB = ((unsigned)(ty0 + k2 - 1) < IMG) ? 1.0f : 0.0f;
        float hp2 = vB * hs(SKP, k2);
        float ht2 = vB * hs(SKT, k2);
        float pn = hp0 + hp1 + hp2;
        float tn = ht0 + ht1 + ht2;
        float ps = SKP[(ry0 + r + 1) * SKW + cx + 1];
        float ts = SKT[(ry0 + r + 1) * SKW + cx + 1];
        float pon = (ps > 0.5f) ? 1.0f : 0.0f;
        float ton = (ts > 0.5f) ? 1.0f : 0.0f;
        float pe = (pn == 2.0f) ? pon : 0.0f;
        float te = (tn == 2.0f) ? ton : 0.0f;
        float pc = (pn >= 4.0f) ? pon : 0.0f;
        float tc = (tn >= 4.0f) ? ton : 0.0f;
        float ds = ps - ts, de = pe - te, dc = pc - tc;
        acc += 0.6f * ds * ds + 0.2f * (de * de + dc * dc);
        hp0 = hp1; hp1 = hp2;
        ht0 = ht1; ht1 = ht2;
    }

    #pragma unroll
    for (int off = 32; off >= 1; off >>= 1)
        acc += __shfl_down(acc, off, 64);
    if ((tid & 63) == 0) red[tid >> 6] = acc;
    __syncthreads();
    if (tid == 0) {
        float sum = red[0] + red[1] + red[2] + red[3];
        atomicAdd(out, sum * (1.0f / 8388608.0f));  // N = 32*512*512 = 2^23
    }
}

extern "C" void kernel_launch(void* const* d_in, const int* in_sizes, int n_in,
                              void* d_out, int out_size, void* d_ws, size_t ws_size,
                              hipStream_t stream) {
    const float* pred   = (const float*)d_in[0];
    const float* target = (const float*)d_in[1];
    float* out = (float*)d_out;
    hipMemsetAsync(d_out, 0, sizeof(float) * (out_size > 0 ? out_size : 1), stream);
    const int nblocks = 32 * 64;   // 32 images x (4x16) tiles
    skel_conn_loss<<<nblocks, NT, 0, stream>>>(pred, target, out);
}